// Round 1
// baseline (134.871 us; speedup 1.0000x reference)
//
#include <hip/hip_runtime.h>
#include <math.h>

// Problem constants (from reference setup_inputs)
#define BB 16
#define NN 2048
#define MM 32
#define PP 48
#define NTYPE 5
#define CC 240              // PP * NTYPE
#define PAIRS 32            // (b,n) pairs per block
#define BLOCK 256

// Kernel A: compute layer[b,n, t*48+p] and per-n sum / sumsq partials.
__global__ __launch_bounds__(BLOCK) void acp_compute(
    const float* __restrict__ X,      // [B,N,3]
    const float* __restrict__ rc,     // [P]
    const float* __restrict__ rs,     // [P]
    const float* __restrict__ re,     // [P]
    const int*   __restrict__ Nbrs,   // [B,N,M]
    const int*   __restrict__ NbrsZ,  // [B,N,M]
    float* __restrict__ out,          // [B,N,240]
    float* __restrict__ wsum,         // [N]
    float* __restrict__ wsq)          // [N]
{
    __shared__ float sR[PAIRS * MM];
    __shared__ int   sT[PAIRS * MM];
    __shared__ float s_rc[PP], s_rs[PP], s_re[PP], s_pioc[PP];
    __shared__ float redS[PAIRS], redQ[PAIRS];

    const int tid = threadIdx.x;
    const int bn0 = blockIdx.x * PAIRS;

    if (tid < PP) {
        float rcv = rc[tid];
        s_rc[tid]   = rcv;
        s_rs[tid]   = rs[tid];
        s_re[tid]   = re[tid];
        s_pioc[tid] = 3.14159265358979323846f / rcv;
    }
    if (tid < PAIRS) { redS[tid] = 0.0f; redQ[tid] = 0.0f; }

    // ---- Phase 1: distances + type index into LDS ----
    #pragma unroll
    for (int k = 0; k < (PAIRS * MM) / BLOCK; ++k) {
        int idx = tid + k * BLOCK;          // 0..1023
        int c = idx >> 5;                   // pair within block
        int m = idx & 31;                   // neighbor
        int bn = bn0 + c;
        int b  = bn >> 11;                  // N = 2048
        int nb = Nbrs[bn * MM + m];
        int z  = NbrsZ[bn * MM + m];
        const float* xo = X + (size_t)bn * 3;
        const float* xn = X + ((size_t)b * NN + nb) * 3;
        float dx = xn[0] - xo[0];
        float dy = xn[1] - xo[1];
        float dz = xn[2] - xo[2];
        sR[idx] = sqrtf(dx * dx + dy * dy + dz * dz);
        int t = (z == 1) ? 0 : (z == 6) ? 1 : (z == 7) ? 2
              : (z == 8) ? 3 : (z == 16) ? 4 : -1;
        sT[idx] = t;
    }
    __syncthreads();

    // ---- Phase 2: radial symmetry functions, per-type sums ----
    #pragma unroll
    for (int k = 0; k < (PAIRS * PP) / BLOCK; ++k) {
        int j = tid + k * BLOCK;            // 0..1535
        int c = j / PP;
        int p = j - c * PP;
        float rcv  = s_rc[p];
        float rsv  = s_rs[p];
        float rev  = s_re[p];
        float pioc = s_pioc[p];
        float a0 = 0.f, a1 = 0.f, a2 = 0.f, a3 = 0.f, a4 = 0.f;
        const float* Rrow = sR + c * MM;
        const int*   Trow = sT + c * MM;
        #pragma unroll 8
        for (int m = 0; m < MM; ++m) {
            float R = Rrow[m];
            int   t = Trow[m];
            float d = R - rsv;
            float w = __expf(-rev * d * d);
            float fc = 0.5f * __cosf(pioc * R) + 0.5f;
            float v = (R <= rcv) ? w * fc : 0.0f;
            a0 += (t == 0) ? v : 0.0f;
            a1 += (t == 1) ? v : 0.0f;
            a2 += (t == 2) ? v : 0.0f;
            a3 += (t == 3) ? v : 0.0f;
            a4 += (t == 4) ? v : 0.0f;
        }
        int bn = bn0 + c;
        float* o = out + (size_t)bn * CC + p;
        o[0]       = a0;
        o[PP]      = a1;
        o[2 * PP]  = a2;
        o[3 * PP]  = a3;
        o[4 * PP]  = a4;
        float s1 = a0 + a1 + a2 + a3 + a4;
        float s2 = a0 * a0 + a1 * a1 + a2 * a2 + a3 * a3 + a4 * a4;
        atomicAdd(&redS[c], s1);
        atomicAdd(&redQ[c], s2);
    }
    __syncthreads();

    if (tid < PAIRS) {
        int n = (bn0 + tid) & (NN - 1);
        atomicAdd(&wsum[n], redS[tid]);
        atomicAdd(&wsq[n], redQ[tid]);
    }
}

// Kernel B: in-place BatchNorm normalize, float4-vectorized.
// 240 floats per (b,n) = 60 float4s; all 4 lanes of a float4 share n.
__global__ __launch_bounds__(BLOCK) void acp_norm(
    float* __restrict__ out,
    const float* __restrict__ wsum,
    const float* __restrict__ wsq)
{
    int id = blockIdx.x * BLOCK + threadIdx.x;
    const int total4 = BB * NN * CC / 4;    // 1966080
    if (id >= total4) return;
    int bn = id / 60;                       // 60 float4 per (b,n)
    int n  = bn & (NN - 1);
    const float cnt_inv = 1.0f / (float)(BB * CC);   // 1/3840
    float s1 = wsum[n];
    float s2 = wsq[n];
    float mean = s1 * cnt_inv;
    float var  = s2 * cnt_inv - mean * mean;
    float rstd = rsqrtf(var + 1e-5f);
    float4* o4 = (float4*)out;
    float4 v = o4[id];
    v.x = (v.x - mean) * rstd;
    v.y = (v.y - mean) * rstd;
    v.z = (v.z - mean) * rstd;
    v.w = (v.w - mean) * rstd;
    o4[id] = v;
}

extern "C" void kernel_launch(void* const* d_in, const int* in_sizes, int n_in,
                              void* d_out, int out_size, void* d_ws, size_t ws_size,
                              hipStream_t stream) {
    const float* X    = (const float*)d_in[0];
    const float* rc   = (const float*)d_in[1];
    const float* rs   = (const float*)d_in[2];
    const float* re   = (const float*)d_in[3];
    const int*   Nbrs = (const int*)d_in[4];
    const int*   NbrsZ= (const int*)d_in[5];
    float* out = (float*)d_out;

    float* wsum = (float*)d_ws;          // [2048]
    float* wsq  = wsum + NN;             // [2048]

    hipMemsetAsync(d_ws, 0, 2 * NN * sizeof(float), stream);

    int blocksA = (BB * NN) / PAIRS;     // 1024
    acp_compute<<<blocksA, BLOCK, 0, stream>>>(X, rc, rs, re, Nbrs, NbrsZ,
                                               out, wsum, wsq);

    int total4 = BB * NN * CC / 4;
    int blocksB = (total4 + BLOCK - 1) / BLOCK;   // 7680
    acp_norm<<<blocksB, BLOCK, 0, stream>>>(out, wsum, wsq);
}

// Round 2
// 94.417 us; speedup vs baseline: 1.4285x; 1.4285x over previous
//
#include <hip/hip_runtime.h>
#include <math.h>

// B=16, N=2048, M=32, P=48, T=5, C=240
#define NN 2048
#define MM 32
#define PP 48
#define CC 240
#define PI_F 3.14159265358979323846f

// One block handles 2 n-values x all 16 batches = 32 (b,n) pairs.
// Pair index c = j*16 + b, j = n - n0 in {0,1}.
// Thread = (c = tid>>3, p-chunk pg = tid&7 -> p in [pg*6, pg*6+6)).
__global__ __launch_bounds__(256) void acp_fused(
    const float* __restrict__ X,      // [B,N,3]
    const float* __restrict__ rc,     // [P]
    const float* __restrict__ rs,     // [P]
    const float* __restrict__ re,     // [P]
    const int*   __restrict__ Nbrs,   // [B,N,M]
    const int*   __restrict__ NbrsZ,  // [B,N,M]
    float* __restrict__ out)          // [B,N,240]
{
    __shared__ float sRs[32 * 33];    // type-sorted R per pair, stride 33 (pad)
    __shared__ int   sCnt[32 * 8];    // per-pair per-type counts
    __shared__ int   sBase[32 * 8];   // per-pair per-type segment starts
    __shared__ float sPrs[PP], sPre[PP], sPpi[PP];
    __shared__ float redS[2], redQ[2];

    const int tid = threadIdx.x;
    const int n0 = blockIdx.x * 2;

    if (tid < PP) {
        sPrs[tid] = rs[tid];
        sPre[tid] = -re[tid];             // exp(-re*d^2) = __expf(sPre*d*d)
        sPpi[tid] = PI_F / rc[tid];
    }
    if (tid < 2) { redS[tid] = 0.0f; redQ[tid] = 0.0f; }
    sCnt[tid] = 0;                        // 256 = 32*8 exactly
    __syncthreads();

    // ---- Phase 1: distances + counting-sort by type (invalid dropped) ----
    float r4[4];
    int   t4[4], pos4[4];
    #pragma unroll
    for (int k = 0; k < 4; ++k) {
        int idx = tid + k * 256;          // 0..1023
        int c = idx >> 5;                 // pair
        int m = idx & 31;
        int b = c & 15;
        int j = c >> 4;
        int bn = b * NN + (n0 + j);
        int nb = Nbrs[bn * MM + m];
        int z  = NbrsZ[bn * MM + m];
        const float* xo = X + (size_t)bn * 3;
        const float* xn = X + (size_t)(b * NN + nb) * 3;
        float dx = xn[0] - xo[0];
        float dy = xn[1] - xo[1];
        float dz = xn[2] - xo[2];
        r4[k] = sqrtf(dx * dx + dy * dy + dz * dz);
        int t = (z == 1) ? 0 : (z == 6) ? 1 : (z == 7) ? 2
              : (z == 8) ? 3 : (z == 16) ? 4 : -1;
        t4[k] = t;
        pos4[k] = (t >= 0) ? atomicAdd(&sCnt[c * 8 + t], 1) : 0;
    }
    __syncthreads();
    if (tid < 32) {
        int s = 0;
        #pragma unroll
        for (int t = 0; t < 5; ++t) { sBase[tid * 8 + t] = s; s += sCnt[tid * 8 + t]; }
    }
    __syncthreads();
    #pragma unroll
    for (int k = 0; k < 4; ++k) {
        if (t4[k] >= 0) {
            int c = (tid + k * 256) >> 5;
            sRs[c * 33 + sBase[c * 8 + t4[k]] + pos4[k]] = r4[k];
        }
    }
    __syncthreads();

    // ---- Phase 2: radial symmetry functions over valid neighbors only ----
    const int c  = tid >> 3;              // 0..31
    const int pg = tid & 7;
    const int p0 = pg * 6;

    float prs[6], pre[6], ppi[6];
    #pragma unroll
    for (int i = 0; i < 6; ++i) {
        prs[i] = sPrs[p0 + i];
        pre[i] = sPre[p0 + i];
        ppi[i] = sPpi[p0 + i];
    }

    float acc[5][6];
    #pragma unroll
    for (int t = 0; t < 5; ++t)
        #pragma unroll
        for (int i = 0; i < 6; ++i) acc[t][i] = 0.0f;

    const float* Rrow = sRs + c * 33;
    #pragma unroll
    for (int t = 0; t < 5; ++t) {
        int s = sBase[c * 8 + t];
        int e = s + sCnt[c * 8 + t];
        for (int m = s; m < e; ++m) {      // per-lane bounds -> exec-masked loop
            float R = Rrow[m];
            #pragma unroll
            for (int i = 0; i < 6; ++i) {
                float d  = R - prs[i];
                float w  = __expf(pre[i] * d * d);
                float a  = fminf(R * ppi[i], PI_F);   // cutoff: cos(pi)=-1 -> fc=0
                float fc = fmaf(0.5f, __cosf(a), 0.5f);
                acc[t][i] += w * fc;
            }
        }
    }

    // ---- Epilogue: block-local BN stats (per n over 16 b x 240 c = 3840) ----
    float s1 = 0.0f, s2 = 0.0f;
    #pragma unroll
    for (int t = 0; t < 5; ++t)
        #pragma unroll
        for (int i = 0; i < 6; ++i) {
            float v = acc[t][i];
            s1 += v;
            s2 = fmaf(v, v, s2);
        }
    // each wave covers a single j (waves 0,1 -> j=0; waves 2,3 -> j=1)
    #pragma unroll
    for (int k = 1; k < 64; k <<= 1) {
        s1 += __shfl_xor(s1, k, 64);
        s2 += __shfl_xor(s2, k, 64);
    }
    const int j = c >> 4;
    if ((tid & 63) == 0) {
        atomicAdd(&redS[j], s1);
        atomicAdd(&redQ[j], s2);
    }
    __syncthreads();

    const float cnt_inv = 1.0f / 3840.0f;
    float mean = redS[j] * cnt_inv;
    float var  = redQ[j] * cnt_inv - mean * mean;
    float rstd = rsqrtf(var + 1e-5f);

    const int b  = c & 15;
    const int bn = b * NN + (n0 + j);
    float* o = out + (size_t)bn * CC;
    #pragma unroll
    for (int t = 0; t < 5; ++t) {
        float nv[6];
        #pragma unroll
        for (int i = 0; i < 6; ++i) nv[i] = (acc[t][i] - mean) * rstd;
        float2* o2 = (float2*)(o + t * PP + p0);   // 24B-aligned (p0 mult of 6)
        o2[0] = make_float2(nv[0], nv[1]);
        o2[1] = make_float2(nv[2], nv[3]);
        o2[2] = make_float2(nv[4], nv[5]);
    }
}

extern "C" void kernel_launch(void* const* d_in, const int* in_sizes, int n_in,
                              void* d_out, int out_size, void* d_ws, size_t ws_size,
                              hipStream_t stream) {
    const float* X     = (const float*)d_in[0];
    const float* rc    = (const float*)d_in[1];
    const float* rs    = (const float*)d_in[2];
    const float* re    = (const float*)d_in[3];
    const int*   Nbrs  = (const int*)d_in[4];
    const int*   NbrsZ = (const int*)d_in[5];
    float* out = (float*)d_out;

    acp_fused<<<NN / 2, 256, 0, stream>>>(X, rc, rs, re, Nbrs, NbrsZ, out);
}

// Round 3
// 94.044 us; speedup vs baseline: 1.4341x; 1.0040x over previous
//
#include <hip/hip_runtime.h>
#include <math.h>

// B=16, N=2048, M=32, P=48, T=5, C=240
#define NN 2048
#define MM 32
#define PP 48
#define CC 240
#define PI_F 3.14159265358979323846f

// Block = 1024 threads = 16 waves; one block per n, one wave per (b,n) pair.
// Lane l -> filter p = l (lanes 48..63 duplicate p = l-48, results discarded).
// Neighbors counting-sorted by atom type in LDS; segment bounds are
// wave-uniform -> zero divergence in the hot loop; R is a broadcast LDS read.
__global__ __launch_bounds__(1024) void acp_fused(
    const float* __restrict__ X,      // [B,N,3]
    const float* __restrict__ rc,     // [P]
    const float* __restrict__ rs,     // [P]
    const float* __restrict__ re,     // [P]
    const int*   __restrict__ Nbrs,   // [B,N,M]
    const int*   __restrict__ NbrsZ,  // [B,N,M]
    float* __restrict__ out)          // [B,N,240]
{
    __shared__ float sRs[16 * 33];    // type-sorted R per pair (b), stride 33
    __shared__ int   sCnt[16 * 8];    // per-b per-type counts
    __shared__ int   sBase[16 * 8];   // per-b per-type segment starts
    __shared__ float sPrs[PP], sPre[PP], sPpi[PP];
    __shared__ float redS, redQ;

    const int tid = threadIdx.x;
    const int n = blockIdx.x;

    if (tid < PP) {
        sPrs[tid] = rs[tid];
        sPre[tid] = -re[tid];              // exp(-re*d^2) = __expf(sPre*d*d)
        sPpi[tid] = PI_F / rc[tid];
    }
    if (tid == 0) { redS = 0.0f; redQ = 0.0f; }
    if (tid < 128) sCnt[tid] = 0;
    __syncthreads();

    // ---- Phase 1: gather + distance + counting-sort by type (512 nbrs) ----
    float Rv = 0.0f;
    int   tv = -1, posv = 0, cv = 0;
    if (tid < 512) {
        int c = tid >> 5;                  // b index 0..15
        int m = tid & 31;
        int bn = c * NN + n;
        int nb = Nbrs[bn * MM + m];
        int z  = NbrsZ[bn * MM + m];
        int t = (z == 1) ? 0 : (z == 6) ? 1 : (z == 7) ? 2
              : (z == 8) ? 3 : (z == 16) ? 4 : -1;
        if (t >= 0) {
            const float* xo = X + (size_t)bn * 3;
            const float* xn = X + (size_t)(c * NN + nb) * 3;
            float dx = xn[0] - xo[0];
            float dy = xn[1] - xo[1];
            float dz = xn[2] - xo[2];
            Rv = sqrtf(dx * dx + dy * dy + dz * dz);
            posv = atomicAdd(&sCnt[c * 8 + t], 1);
            tv = t; cv = c;
        }
    }
    __syncthreads();
    if (tid < 16) {
        int s = 0;
        #pragma unroll
        for (int t = 0; t < 5; ++t) { sBase[tid * 8 + t] = s; s += sCnt[tid * 8 + t]; }
    }
    __syncthreads();
    if (tv >= 0) sRs[cv * 33 + sBase[cv * 8 + tv] + posv] = Rv;
    __syncthreads();

    // ---- Phase 2: wave-uniform segmented loop, lane = filter p ----
    const int wv   = tid >> 6;             // b index (wave id) 0..15
    const int lane = tid & 63;
    const int p    = (lane < 48) ? lane : lane - 48;

    const float prs = sPrs[p];
    const float pre = sPre[p];
    const float ppi = sPpi[p];

    float acc[5];
    const float* Rrow = sRs + wv * 33;
    #pragma unroll
    for (int t = 0; t < 5; ++t) {
        acc[t] = 0.0f;
        int s = sBase[wv * 8 + t];         // wave-uniform
        int e = s + sCnt[wv * 8 + t];      // wave-uniform
        for (int m = s; m < e; ++m) {
            float R  = Rrow[m];            // broadcast LDS read
            float d  = R - prs;
            float w  = __expf(pre * d * d);
            float a  = fminf(R * ppi, PI_F);   // R>rc -> cos(pi) -> fc=0
            float fc = fmaf(0.5f, __cosf(a), 0.5f);
            acc[t] += w * fc;
        }
    }

    // ---- Epilogue: fused BatchNorm over (16 b x 240 c) = 3840 values ----
    float s1 = 0.0f, s2 = 0.0f;
    if (lane < 48) {
        #pragma unroll
        for (int t = 0; t < 5; ++t) {
            s1 += acc[t];
            s2 = fmaf(acc[t], acc[t], s2);
        }
    }
    #pragma unroll
    for (int k = 1; k < 64; k <<= 1) {
        s1 += __shfl_xor(s1, k, 64);
        s2 += __shfl_xor(s2, k, 64);
    }
    if (lane == 0) {
        atomicAdd(&redS, s1);
        atomicAdd(&redQ, s2);
    }
    __syncthreads();

    const float cnt_inv = 1.0f / 3840.0f;
    float mean = redS * cnt_inv;
    float var  = redQ * cnt_inv - mean * mean;
    float rstd = rsqrtf(var + 1e-5f);

    if (lane < 48) {
        float* o = out + ((size_t)wv * NN + n) * CC + p;
        #pragma unroll
        for (int t = 0; t < 5; ++t)
            o[t * PP] = (acc[t] - mean) * rstd;
    }
}

extern "C" void kernel_launch(void* const* d_in, const int* in_sizes, int n_in,
                              void* d_out, int out_size, void* d_ws, size_t ws_size,
                              hipStream_t stream) {
    const float* X     = (const float*)d_in[0];
    const float* rc    = (const float*)d_in[1];
    const float* rs    = (const float*)d_in[2];
    const float* re    = (const float*)d_in[3];
    const int*   Nbrs  = (const int*)d_in[4];
    const int*   NbrsZ = (const int*)d_in[5];
    float* out = (float*)d_out;

    acp_fused<<<NN, 1024, 0, stream>>>(X, rc, rs, re, Nbrs, NbrsZ, out);
}

// Round 5
// 88.737 us; speedup vs baseline: 1.5199x; 1.0598x over previous
//
#include <hip/hip_runtime.h>
#include <math.h>

// B=16, N=2048, M=32, P=48, T=5, C=240
#define NN 2048
#define MM 32
#define PP 48
#define CC 240
#define PI_F 3.14159265358979323846f
#define LOG2E_F 1.4426950408889634f

// One block per n: 512 threads = 8 waves; wave w owns pairs (b=w, b=w+8).
// Lane l -> filter p = l (lanes 48..63 duplicate p=l-48, discarded).
// Neighbors counting-sorted by type in LDS; neighbors with R > max(rc)
// dropped at insertion (they contribute exactly 0 for every filter).
// fc = 0.5*(cos(pi R/rc)+1) = cos^2(pi R/(2 rc)); exp via v_exp_f32 with
// log2e folded into the per-filter constant.
__global__ __launch_bounds__(512) void acp_fused(
    const float* __restrict__ X,      // [B,N,3]
    const float* __restrict__ rc,     // [P]
    const float* __restrict__ rs,     // [P]
    const float* __restrict__ re,     // [P]
    const int*   __restrict__ Nbrs,   // [B,N,M]
    const int*   __restrict__ NbrsZ,  // [B,N,M]
    float* __restrict__ out)          // [B,N,240]
{
    __shared__ float sRs[16 * 33];    // type-sorted R per b, stride 33
    __shared__ int   sCnt[16 * 8];
    __shared__ int   sBase[16 * 8];
    __shared__ float sPrs[PP], sPre[PP], sPp2[PP];
    __shared__ float sRcMax;
    __shared__ float redS, redQ;

    const int tid  = threadIdx.x;
    const int n    = blockIdx.x;
    const int lane = tid & 63;
    const int wv   = tid >> 6;        // wave 0..7

    if (tid < PP) {
        sPrs[tid] = rs[tid];
        sPre[tid] = -re[tid] * LOG2E_F;        // exp(-re d^2)=exp2(sPre d^2)
        sPp2[tid] = 0.5f * PI_F / rc[tid];     // half-angle coefficient
    }
    if (wv == 0) {                             // max rc via wave-0 butterfly
        float v = (lane < PP) ? rc[lane] : 0.0f;
        #pragma unroll
        for (int k = 1; k < 64; k <<= 1) v = fmaxf(v, __shfl_xor(v, k, 64));
        if (lane == 0) sRcMax = v;
    }
    if (tid == 0) { redS = 0.0f; redQ = 0.0f; }
    if (tid < 128) sCnt[tid] = 0;
    __syncthreads();

    // ---- Phase 1: gather + distance + counting-sort (all 512 threads) ----
    const float rcmax = sRcMax;
    float Rv = 0.0f;
    int   tv = -1, posv = 0, cv = tid >> 5;
    {
        int c  = cv;                  // b index 0..15
        int m  = tid & 31;
        int bn = c * NN + n;
        int nb = Nbrs[bn * MM + m];
        int z  = NbrsZ[bn * MM + m];
        int t = (z == 1) ? 0 : (z == 6) ? 1 : (z == 7) ? 2
              : (z == 8) ? 3 : (z == 16) ? 4 : -1;
        if (t >= 0) {
            const float* xo = X + (size_t)bn * 3;
            const float* xn = X + (size_t)(c * NN + nb) * 3;
            float dx = xn[0] - xo[0];
            float dy = xn[1] - xo[1];
            float dz = xn[2] - xo[2];
            float R = sqrtf(dx * dx + dy * dy + dz * dz);
            if (R <= rcmax) {         // beyond every cutoff -> exact zero
                Rv = R;
                tv = t;
                posv = atomicAdd(&sCnt[c * 8 + t], 1);
            }
        }
    }
    __syncthreads();
    if (tid < 16) {
        int s = 0;
        #pragma unroll
        for (int t = 0; t < 5; ++t) { sBase[tid * 8 + t] = s; s += sCnt[tid * 8 + t]; }
    }
    __syncthreads();
    if (tv >= 0) sRs[cv * 33 + sBase[cv * 8 + tv] + posv] = Rv;
    __syncthreads();

    // ---- Phase 2: wave-uniform segmented loops, lane = filter p ----
    const int p = (lane < PP) ? lane : lane - PP;
    const float prs = sPrs[p];
    const float pre = sPre[p];
    const float pp2 = sPp2[p];

    float acc[2][5];
    #pragma unroll
    for (int g = 0; g < 2; ++g) {
        const int c = wv + g * 8;
        const float* Rrow = sRs + c * 33;
        #pragma unroll
        for (int t = 0; t < 5; ++t) {
            int s = sBase[c * 8 + t];          // wave-uniform (SGPR loop)
            int e = s + sCnt[c * 8 + t];
            float a = 0.0f;
            for (int m = s; m < e; ++m) {
                float R  = Rrow[m];            // broadcast LDS read
                float d  = R - prs;
                float w  = __builtin_amdgcn_exp2f(pre * d * d);
                float ct = __cosf(fminf(R * pp2, 0.5f * PI_F));
                a = fmaf(w * ct, ct, a);       // w * cos^2
            }
            acc[g][t] = a;
        }
    }

    // ---- Epilogue: fused BatchNorm stats (per n over 16 b x 240 c) ----
    float s1 = 0.0f, s2 = 0.0f;
    if (lane < PP) {
        #pragma unroll
        for (int g = 0; g < 2; ++g)
            #pragma unroll
            for (int t = 0; t < 5; ++t) {
                float v = acc[g][t];
                s1 += v;
                s2 = fmaf(v, v, s2);
            }
    }
    #pragma unroll
    for (int k = 1; k < 64; k <<= 1) {
        s1 += __shfl_xor(s1, k, 64);
        s2 += __shfl_xor(s2, k, 64);
    }
    if (lane == 0) {
        atomicAdd(&redS, s1);
        atomicAdd(&redQ, s2);
    }
    __syncthreads();

    const float cnt_inv = 1.0f / 3840.0f;
    float mean = redS * cnt_inv;
    float var  = redQ * cnt_inv - mean * mean;
    float rstd = rsqrtf(var + 1e-5f);

    if (lane < PP) {
        #pragma unroll
        for (int g = 0; g < 2; ++g) {
            const int c = wv + g * 8;
            float* o = out + ((size_t)c * NN + n) * CC + p;
            #pragma unroll
            for (int t = 0; t < 5; ++t)
                o[t * PP] = (acc[g][t] - mean) * rstd;
        }
    }
}

extern "C" void kernel_launch(void* const* d_in, const int* in_sizes, int n_in,
                              void* d_out, int out_size, void* d_ws, size_t ws_size,
                              hipStream_t stream) {
    const float* X     = (const float*)d_in[0];
    const float* rc    = (const float*)d_in[1];
    const float* rs    = (const float*)d_in[2];
    const float* re    = (const float*)d_in[3];
    const int*   Nbrs  = (const int*)d_in[4];
    const int*   NbrsZ = (const int*)d_in[5];
    float* out = (float*)d_out;

    acp_fused<<<NN, 512, 0, stream>>>(X, rc, rs, re, Nbrs, NbrsZ, out);
}